// Round 16
// baseline (303.247 us; speedup 1.0000x reference)
//
#include <hip/hip_runtime.h>

#define NNODES 100000
#define NEDGES 1600000
#define DINP   128
#define HDIM   64
#define NLAYERS 2

#define NBUCK 256
#define BDIV  391
#define TILE  8192
#define NT    ((NEDGES + TILE - 1) / TILE)     // 196
#define NTOT  (NBUCK * NT)                     // 50176
#define SEG   (NTOT / 1024)                    // 49
#define EMB_BLOCKS 1563                        // ceil(6250 waves / 4)
#define SUBT 4
#define SEGT (TILE / SUBT)                     // 2048

typedef unsigned short ushort_t;
typedef unsigned int   uint_t;
typedef unsigned char  uchar_t;
typedef __attribute__((ext_vector_type(8))) short bf16x8;
typedef __attribute__((ext_vector_type(4))) float f32x4;
typedef __attribute__((ext_vector_type(2))) float f32x2;

__device__ __forceinline__ ushort_t f32_to_bf16_rne(float x) {
    uint_t u = __float_as_uint(x);
    u = (u + 0x7FFFu + ((u >> 16) & 1u)) >> 16;
    return (ushort_t)u;
}
__device__ __forceinline__ float bf16_to_f32(ushort_t v) {
    return __uint_as_float(((uint_t)v) << 16);
}
__device__ __forceinline__ uint_t pack_bf16(float lo, float hi) {
    return (uint_t)f32_to_bf16_rne(lo) | ((uint_t)f32_to_bf16_rne(hi) << 16);
}

// sigma-permuted column layout: original col c stored at pos 4*(c&15)+(c>>4);
// pos p holds col (p&3)*16 + (p>>2). Applied to hbf/hq8/aggbf; compensated in
// wprep by permuting k. dense<0> fp32 output remains standard.

// ---------------------------------------------------------------------------
// fused wprep: emb B-fragments (t<8192) + W1/W2/W3 B-fragments (t>=8192)
// ---------------------------------------------------------------------------
__global__ __launch_bounds__(256) void wprep_all(
    const float* __restrict__ Wemb, const float* __restrict__ W1,
    const float* __restrict__ W2, const float* __restrict__ W3,
    ushort_t* __restrict__ wefrag, ushort_t* __restrict__ wfrag)
{
    int t = blockIdx.x * 256 + threadIdx.x;
    if (t < 8192) {
        int j  = t & 7;
        int l  = (t >> 3) & 63;
        int nt = (t >> 9) & 3;
        int kb = (t >> 11) & 3;
        int k = kb * 32 + 8 * (l >> 4) + j;
        int n = nt * 16 + (l & 15);
        float w = Wemb[k * HDIM + n];
        ushort_t hi = f32_to_bf16_rne(w);
        ushort_t lo = f32_to_bf16_rne(w - bf16_to_f32(hi));
        wefrag[(((0 * 4 + kb) * 4 + nt) * 64 + l) * 8 + j] = hi;
        wefrag[(((1 * 4 + kb) * 4 + nt) * 64 + l) * 8 + j] = lo;
    } else {
        int u = t - 8192;
        if (u >= 2 * 3 * 2 * 4 * 64 * 8) return;
        int j    = u & 7;
        int l    = (u >> 3) & 63;
        int nt   = (u >> 9) & 3;
        int kb   = (u >> 11) & 1;
        int mat  = (u >> 12) % 3;
        int layer = u / 12288;
        int kp = kb * 32 + 8 * (l >> 4) + j;       // position in A fragment
        int k  = (kp & 3) * 16 + (kp >> 2);        // sigma: original col there
        int n = nt * 16 + (l & 15);
        const float* Wm = (mat == 0) ? W1 : (mat == 1) ? W2 : W3;
        float w = Wm[(size_t)layer * HDIM * HDIM + k * HDIM + n];
        ushort_t hi = f32_to_bf16_rne(w);
        ushort_t lo = f32_to_bf16_rne(w - bf16_to_f32(hi));
        size_t base = (size_t)layer * 24576;
        wfrag[base + ((((size_t)(mat * 2 + 0) * 2 + kb) * 4 + nt) * 64 + l) * 8 + j] = hi;
        wfrag[base + ((((size_t)(mat * 2 + 1) * 2 + kb) * 4 + nt) * 64 + l) * 8 + j] = lo;
    }
}

// ---------------------------------------------------------------------------
// fused: emb via MFMA (blocks < EMB_BLOCKS) + p1 tile histogram (rest)
// ---------------------------------------------------------------------------
__global__ __launch_bounds__(256) void emb_p1(
    const float* __restrict__ x, const ushort_t* __restrict__ wefrag,
    const float* __restrict__ bemb, ushort_t* __restrict__ hbf,
    uchar_t* __restrict__ hq8,
    const int* __restrict__ dst, int* __restrict__ tileOff)
{
    __shared__ int hist[NBUCK];
    if (blockIdx.x < EMB_BLOCKS) {
        const int wid = blockIdx.x * 4 + (threadIdx.x >> 6);
        if (wid >= NNODES / 16) return;
        const int lane = threadIdx.x & 63;
        const int lrow = lane & 15;
        const int lgrp = lane >> 4;
        const int r0 = wid * 16;

        f32x4 acc[4];
#pragma unroll
        for (int nt = 0; nt < 4; ++nt) acc[nt] = (f32x4){0.f, 0.f, 0.f, 0.f};

#pragma unroll
        for (int kb = 0; kb < 4; ++kb) {
            const float* xp = x + (size_t)(r0 + lrow) * DINP + kb * 32 + lgrp * 8;
            float4 xa = *(const float4*)xp;
            float4 xb = *(const float4*)(xp + 4);
            bf16x8 xhi;
            xhi[0] = (short)f32_to_bf16_rne(xa.x);
            xhi[1] = (short)f32_to_bf16_rne(xa.y);
            xhi[2] = (short)f32_to_bf16_rne(xa.z);
            xhi[3] = (short)f32_to_bf16_rne(xa.w);
            xhi[4] = (short)f32_to_bf16_rne(xb.x);
            xhi[5] = (short)f32_to_bf16_rne(xb.y);
            xhi[6] = (short)f32_to_bf16_rne(xb.z);
            xhi[7] = (short)f32_to_bf16_rne(xb.w);
#pragma unroll
            for (int nt = 0; nt < 4; ++nt) {
                bf16x8 bhi = *(const bf16x8*)(wefrag + (((0 * 4 + kb) * 4 + nt) * 64 + lane) * 8);
                bf16x8 blo = *(const bf16x8*)(wefrag + (((1 * 4 + kb) * 4 + nt) * 64 + lane) * 8);
                acc[nt] = __builtin_amdgcn_mfma_f32_16x16x32_bf16(xhi, bhi, acc[nt], 0, 0, 0);
                acc[nt] = __builtin_amdgcn_mfma_f32_16x16x32_bf16(xhi, blo, acc[nt], 0, 0, 0);
            }
        }

        float bv[4];
#pragma unroll
        for (int nt = 0; nt < 4; ++nt) bv[nt] = bemb[nt * 16 + lrow];

#pragma unroll
        for (int r = 0; r < 4; ++r) {
            int row = r0 + lgrp * 4 + r;
            float o[4];
#pragma unroll
            for (int nt = 0; nt < 4; ++nt) o[nt] = acc[nt][r] + bv[nt];
            uint2 hb;
            hb.x = pack_bf16(o[0], o[1]);
            hb.y = pack_bf16(o[2], o[3]);
            *(uint2*)(hbf + ((size_t)row << 6) + (lrow << 2)) = hb;
            int q = __builtin_amdgcn_cvt_pk_fp8_f32(o[0], o[1], 0, false);
            q = __builtin_amdgcn_cvt_pk_fp8_f32(o[2], o[3], q, true);
            *(int*)(hq8 + ((size_t)row << 6) + (lrow << 2)) = q;
        }
    } else {
        const int tl = blockIdx.x - EMB_BLOCKS, t = threadIdx.x;
        hist[t] = 0;
        __syncthreads();
        const int base = tl * TILE;
#pragma unroll
        for (int i = 0; i < TILE / 256; ++i) {
            int e = base + i * 256 + t;
            if (e < NEDGES) atomicAdd(&hist[dst[e] / BDIV], 1);
        }
        __syncthreads();
        tileOff[t * NT + tl] = hist[t];
    }
}

// ---------------------------------------------------------------------------
// CSR build: p2 scan (writes tileOff + mutable cursor copy gcur)
// ---------------------------------------------------------------------------
__global__ __launch_bounds__(1024) void p2_scan(
    int* __restrict__ tileOff, int* __restrict__ gcur)
{
    __shared__ int sd[1024];
    const int t = threadIdx.x;
    const int lo = t * SEG;
    int s = 0;
    for (int i = 0; i < SEG; ++i) s += tileOff[lo + i];
    sd[t] = s;
    __syncthreads();
    for (int off = 1; off < 1024; off <<= 1) {
        int v = (t >= off) ? sd[t - off] : 0;
        __syncthreads();
        sd[t] += v;
        __syncthreads();
    }
    int run = sd[t] - s;
    for (int i = 0; i < SEG; ++i) {
        int c = tileOff[lo + i];
        tileOff[lo + i] = run;
        gcur[lo + i] = run;
        run += c;
    }
}

// p3: bin edges into tmp via global atomic cursors (784 blocks, no LDS)
__global__ __launch_bounds__(256) void p3_bin(
    const int* __restrict__ src, const int* __restrict__ dst,
    const float* __restrict__ attr, int* __restrict__ gcur,
    int2* __restrict__ tmp)
{
    const int tl = blockIdx.x >> 2;
    const int sb = blockIdx.x & 3;
    const int base = tl * TILE + sb * SEGT;
    const int t = threadIdx.x;
#pragma unroll
    for (int i = 0; i < SEGT / 256; ++i) {
        int e = base + i * 256 + t;
        if (e < NEDGES) {
            int d  = dst[e];
            int bk = d / BDIV;
            int ld = d - bk * BDIV;
            int pos = atomicAdd(&gcur[bk * NT + tl], 1);
            int2 p;
            p.x = (ld << 17) | src[e];
            p.y = __float_as_int(attr[e]);
            tmp[pos] = p;
        }
    }
}

// per-bucket: hist+scan -> rowptr; scatter (src pre-scaled <<6); degw in LDS
__global__ __launch_bounds__(256) void p4_sort(
    const int2* __restrict__ tmp, const int* __restrict__ tileOff,
    int2* __restrict__ edgeS, int* __restrict__ rowptr,
    float* __restrict__ degw)
{
    __shared__ int sdh[512];
    __shared__ int cur[BDIV + 1];
    __shared__ float sdw[BDIV];
    const int b = blockIdx.x, t = threadIdx.x;
    const int n0 = b * BDIV;
    const int nn = (NNODES - n0 < BDIV) ? (NNODES - n0) : BDIV;
    const int ebeg = tileOff[b * NT];
    const int eend = (b + 1 < NBUCK) ? tileOff[(b + 1) * NT] : NEDGES;

    sdh[t] = 0; sdh[t + 256] = 0;
    for (int i = t; i < BDIV; i += 256) sdw[i] = 0.f;
    __syncthreads();
    for (int e = ebeg + t; e < eend; e += 256)
        atomicAdd(&sdh[tmp[e].x >> 17], 1);
    __syncthreads();
    for (int off = 1; off < 512; off <<= 1) {
        int i0 = t, i1 = t + 256;
        int v0 = (i0 >= off) ? sdh[i0 - off] : 0;
        int v1 = (i1 >= off) ? sdh[i1 - off] : 0;
        __syncthreads();
        sdh[i0] += v0; sdh[i1] += v1;
        __syncthreads();
    }
    for (int i = t; i < nn; i += 256) {
        int c = ebeg + (i ? sdh[i - 1] : 0);
        cur[i] = c;
        rowptr[n0 + i] = c;
    }
    if (b == NBUCK - 1 && t == 0) rowptr[NNODES] = NEDGES;
    __syncthreads();
    for (int e = ebeg + t; e < eend; e += 256) {
        int2 w = tmp[e];
        int ld = w.x >> 17;
        int pos = atomicAdd(&cur[ld], 1);
        atomicAdd(&sdw[ld], __int_as_float(w.y));
        int2 p;
        p.x = (w.x & 0x1FFFF) << 6;     // pre-scaled byte offset of src row
        p.y = w.y;
        edgeS[pos] = p;
    }
    __syncthreads();
    for (int i = t; i < nn; i += 256) degw[n0 + i] = sdw[i];
}

// ---------------------------------------------------------------------------
// gather: aggbf[v] = bf16( sum w_e * hq8[src_e] )
// FOUR nodes per wave (16 lanes each) -> 4 independent miss chains per wave.
// Within a 16-lane group: oct = edge slot (2/iter), ol = byte octet (8 fp8
// cols). Reduce = 1 shfl round (bit 3).
// ---------------------------------------------------------------------------
__global__ __launch_bounds__(256) void gather_kernel(
    const int* __restrict__ rowptr, const int2* __restrict__ edgeS,
    const uchar_t* __restrict__ hq8, ushort_t* __restrict__ aggbf)
{
    const int v   = blockIdx.x * 16 + (threadIdx.x >> 4);  // node per 16 lanes
    const int t4  = threadIdx.x & 15;
    const int oct = t4 >> 3;            // edge slot 0..1
    const int ol  = t4 & 7;             // cols 8*ol .. 8*ol+7 (perm positions)
    const int beg = rowptr[v], end = rowptr[v + 1];
    const int cnt = end - beg;
    const uchar_t* __restrict__ hq8o = hq8 + (ol << 3);
    const int2* __restrict__ ep = edgeS + beg + oct;

    float a0 = 0.f, a1 = 0.f, a2 = 0.f, a3 = 0.f;
    float a4 = 0.f, a5 = 0.f, a6 = 0.f, a7 = 0.f;
    const int nfull = cnt >> 1;
#pragma unroll 2
    for (int k = 0; k < nfull; ++k) {
        int2 ev = ep[(size_t)k * 2];
        float wv = __int_as_float(ev.y);
        uint2 u = *(const uint2*)(hq8o + ev.x);
        f32x2 f01 = __builtin_amdgcn_cvt_pk_f32_fp8((int)u.x, false);
        f32x2 f23 = __builtin_amdgcn_cvt_pk_f32_fp8((int)u.x, true);
        f32x2 f45 = __builtin_amdgcn_cvt_pk_f32_fp8((int)u.y, false);
        f32x2 f67 = __builtin_amdgcn_cvt_pk_f32_fp8((int)u.y, true);
        a0 += wv * f01[0];  a1 += wv * f01[1];
        a2 += wv * f23[0];  a3 += wv * f23[1];
        a4 += wv * f45[0];  a5 += wv * f45[1];
        a6 += wv * f67[0];  a7 += wv * f67[1];
    }
    if (cnt & 1) {
        int idx = beg + (nfull << 1) + oct;
        bool ok = idx < end;
        int2 ev = edgeS[ok ? idx : beg];
        float wv = ok ? __int_as_float(ev.y) : 0.f;
        uint2 u = *(const uint2*)(hq8o + ev.x);
        f32x2 f01 = __builtin_amdgcn_cvt_pk_f32_fp8((int)u.x, false);
        f32x2 f23 = __builtin_amdgcn_cvt_pk_f32_fp8((int)u.x, true);
        f32x2 f45 = __builtin_amdgcn_cvt_pk_f32_fp8((int)u.y, false);
        f32x2 f67 = __builtin_amdgcn_cvt_pk_f32_fp8((int)u.y, true);
        a0 += wv * f01[0];  a1 += wv * f01[1];
        a2 += wv * f23[0];  a3 += wv * f23[1];
        a4 += wv * f45[0];  a5 += wv * f45[1];
        a6 += wv * f67[0];  a7 += wv * f67[1];
    }

    // reduce across the 2 edge slots (lane bit 3) — stays within 16-lane group
    a0 += __shfl_xor(a0, 8);
    a1 += __shfl_xor(a1, 8);
    a2 += __shfl_xor(a2, 8);
    a3 += __shfl_xor(a3, 8);
    a4 += __shfl_xor(a4, 8);
    a5 += __shfl_xor(a5, 8);
    a6 += __shfl_xor(a6, 8);
    a7 += __shfl_xor(a7, 8);

    if (oct == 0) {
        uint4 o;
        o.x = pack_bf16(a0, a1);
        o.y = pack_bf16(a2, a3);
        o.z = pack_bf16(a4, a5);
        o.w = pack_bf16(a6, a7);
        *(uint4*)(aggbf + ((size_t)v << 6) + (ol << 3)) = o;
    }
}

// ---------------------------------------------------------------------------
// dense via MFMA (A operands permuted, wfrag sigma-compensated)
// ---------------------------------------------------------------------------
template<int WRITE_BF>
__global__ __launch_bounds__(256) void dense_mfma(
    const ushort_t* __restrict__ hbf, const ushort_t* __restrict__ aggbf,
    const float* __restrict__ degw, const ushort_t* __restrict__ wfrag,
    const float* __restrict__ b1, const float* __restrict__ b3,
    float* __restrict__ hout, ushort_t* __restrict__ hbf_out,
    uchar_t* __restrict__ hq8_out)
{
    const int wid = blockIdx.x * 4 + (threadIdx.x >> 6);
    if (wid >= NNODES / 16) return;
    const int lane = threadIdx.x & 63;
    const int lrow = lane & 15;
    const int lgrp = lane >> 4;
    const int r0   = wid * 16;

    f32x4 acc[3][4];
#pragma unroll
    for (int m = 0; m < 3; ++m)
#pragma unroll
        for (int nt = 0; nt < 4; ++nt)
            acc[m][nt] = (f32x4){0.f, 0.f, 0.f, 0.f};

#pragma unroll
    for (int kb = 0; kb < 2; ++kb) {
        const size_t aoff = ((size_t)(r0 + lrow) << 6) + kb * 32 + lgrp * 8;
        bf16x8 a_agg = *(const bf16x8*)(aggbf + aoff);
        bf16x8 a_h   = *(const bf16x8*)(hbf + aoff);
#pragma unroll
        for (int mv = 0; mv < 6; ++mv) {
            const int mat = mv >> 1;
            bf16x8 a = (mat == 0) ? a_agg : a_h;
            const ushort_t* wb = wfrag + (((size_t)mv * 2 + kb) * 4) * 512 + lane * 8;
#pragma unroll
            for (int nt = 0; nt < 4; ++nt) {
                bf16x8 b = *(const bf16x8*)(wb + nt * 512);
                acc[mat][nt] = __builtin_amdgcn_mfma_f32_16x16x32_bf16(
                    a, b, acc[mat][nt], 0, 0, 0);
            }
        }
    }

    float dreg[4];
#pragma unroll
    for (int r = 0; r < 4; ++r) dreg[r] = degw[r0 + lgrp * 4 + r];

    float b1v[4], b3v[4];
#pragma unroll
    for (int nt = 0; nt < 4; ++nt) {
        b1v[nt] = b1[nt * 16 + lrow];
        b3v[nt] = b3[nt * 16 + lrow];
    }

#pragma unroll
    for (int r = 0; r < 4; ++r) {
        int row = r0 + lgrp * 4 + r;
        float o[4];
#pragma unroll
        for (int nt = 0; nt < 4; ++nt) {
            float t = acc[0][nt][r] + acc[2][nt][r] - dreg[r] * acc[1][nt][r]
                    + dreg[r] * b1v[nt] + b3v[nt];
            o[nt] = fmaxf(t, 0.f);
        }
        if (WRITE_BF) {
            uint2 hb;
            hb.x = pack_bf16(o[0], o[1]);
            hb.y = pack_bf16(o[2], o[3]);
            *(uint2*)(hbf_out + ((size_t)row << 6) + (lrow << 2)) = hb;
            int q = __builtin_amdgcn_cvt_pk_fp8_f32(o[0], o[1], 0, false);
            q = __builtin_amdgcn_cvt_pk_fp8_f32(o[2], o[3], q, true);
            *(int*)(hq8_out + ((size_t)row << 6) + (lrow << 2)) = q;
        } else {
#pragma unroll
            for (int nt = 0; nt < 4; ++nt)
                hout[((size_t)row << 6) + nt * 16 + lrow] = o[nt];
        }
    }
}

// ---------------------------------------------------------------------------
extern "C" void kernel_launch(void* const* d_in, const int* in_sizes, int n_in,
                              void* d_out, int out_size, void* d_ws, size_t ws_size,
                              hipStream_t stream)
{
    const float* x    = (const float*)d_in[0];
    const int*   eidx = (const int*)  d_in[1];
    const float* attr = (const float*)d_in[2];
    const float* Wemb = (const float*)d_in[4];
    const float* bemb = (const float*)d_in[5];
    const float* W1   = (const float*)d_in[6];
    const float* b1   = (const float*)d_in[7];
    const float* W2   = (const float*)d_in[8];
    const float* W3   = (const float*)d_in[9];
    const float* b3   = (const float*)d_in[10];

    float* hout = (float*)d_out;

    // workspace layout (4B units)
    float*    degw    = (float*)d_ws;                            // N
    int*      rowptr  = (int*)d_ws + 100000;                     // N+1
    int*      tileOff = (int*)d_ws + 200016;                     // NTOT
    int2*     edgeS   = (int2*)((int*)d_ws + 250192);            // E int2
    ushort_t* hbf     = (ushort_t*)((int*)d_ws + 3450192);       // N*64 bf16 (permuted)
    ushort_t* aggbf   = (ushort_t*)((int*)d_ws + 6650192);       // N*64 bf16 (permuted)
    int2*     tmp     = (int2*)aggbf;                            // alias (CSR build)
    ushort_t* wfrag   = (ushort_t*)((int*)d_ws + 9850192);       // 49152 ushorts
    ushort_t* wefrag  = (ushort_t*)((int*)d_ws + 9874768);       // 16384 ushorts
    uchar_t*  hq8     = (uchar_t*)((int*)d_ws + 9882960);        // N*64 fp8 (permuted)
    int*      gcur    = (int*)d_ws + 11482960;                   // NTOT (cursors)

    const int* srcI = eidx;
    const int* dstI = eidx + NEDGES;

    wprep_all<<<128, 256, 0, stream>>>(Wemb, W1, W2, W3, wefrag, wfrag);

    emb_p1<<<EMB_BLOCKS + NT, 256, 0, stream>>>(
        x, wefrag, bemb, hbf, hq8, dstI, tileOff);

    p2_scan<<<1, 1024, 0, stream>>>(tileOff, gcur);
    p3_bin <<<NT * SUBT, 256, 0, stream>>>(srcI, dstI, attr, gcur, tmp);
    p4_sort<<<NBUCK, 256, 0, stream>>>(tmp, tileOff, edgeS, rowptr, degw);

    const int mfmaGrid = (NNODES / 16 + 3) / 4;   // 1563
    const int gatherGrid = NNODES / 16;           // 4 nodes/wave, 4 waves/block
    // layer 0: writes hbf + hq8
    gather_kernel<<<gatherGrid, 256, 0, stream>>>(rowptr, edgeS, hq8, aggbf);
    dense_mfma<1><<<mfmaGrid, 256, 0, stream>>>(
        hbf, aggbf, degw, wfrag, b1, b3, hout, hbf, hq8);
    // layer 1: writes fp32 output
    gather_kernel<<<gatherGrid, 256, 0, stream>>>(rowptr, edgeS, hq8, aggbf);
    dense_mfma<0><<<mfmaGrid, 256, 0, stream>>>(
        hbf, aggbf, degw, wfrag + 24576, b1 + HDIM, b3 + HDIM, hout, hbf, hq8);
}

// Round 17
// 183.116 us; speedup vs baseline: 1.6560x; 1.6560x over previous
//
#include <hip/hip_runtime.h>

#define NNODES 100000
#define NEDGES 1600000
#define DINP   128
#define HDIM   64
#define NLAYERS 2

#define NBUCK 256
#define BDIV  391
#define TILE  8192
#define NT    ((NEDGES + TILE - 1) / TILE)     // 196
#define NTOT  (NBUCK * NT)                     // 50176
#define SEG   (NTOT / 1024)                    // 49
#define EMB_BLOCKS 1563                        // ceil(6250 waves / 4)

typedef unsigned short ushort_t;
typedef unsigned int   uint_t;
typedef unsigned char  uchar_t;
typedef __attribute__((ext_vector_type(8))) short bf16x8;
typedef __attribute__((ext_vector_type(4))) float f32x4;
typedef __attribute__((ext_vector_type(2))) float f32x2;

__device__ __forceinline__ ushort_t f32_to_bf16_rne(float x) {
    uint_t u = __float_as_uint(x);
    u = (u + 0x7FFFu + ((u >> 16) & 1u)) >> 16;
    return (ushort_t)u;
}
__device__ __forceinline__ float bf16_to_f32(ushort_t v) {
    return __uint_as_float(((uint_t)v) << 16);
}
__device__ __forceinline__ uint_t pack_bf16(float lo, float hi) {
    return (uint_t)f32_to_bf16_rne(lo) | ((uint_t)f32_to_bf16_rne(hi) << 16);
}

// sigma-permuted column layout: original col c stored at pos 4*(c&15)+(c>>4);
// pos p holds col (p&3)*16 + (p>>2). Applied to hbf/hq8/aggbf; compensated in
// wprep by permuting k. dense<0> fp32 output remains standard.

// ---------------------------------------------------------------------------
// fused wprep: emb B-fragments (t<8192) + W1/W2/W3 B-fragments (t>=8192)
// ---------------------------------------------------------------------------
__global__ __launch_bounds__(256) void wprep_all(
    const float* __restrict__ Wemb, const float* __restrict__ W1,
    const float* __restrict__ W2, const float* __restrict__ W3,
    ushort_t* __restrict__ wefrag, ushort_t* __restrict__ wfrag)
{
    int t = blockIdx.x * 256 + threadIdx.x;
    if (t < 8192) {
        int j  = t & 7;
        int l  = (t >> 3) & 63;
        int nt = (t >> 9) & 3;
        int kb = (t >> 11) & 3;
        int k = kb * 32 + 8 * (l >> 4) + j;
        int n = nt * 16 + (l & 15);
        float w = Wemb[k * HDIM + n];
        ushort_t hi = f32_to_bf16_rne(w);
        ushort_t lo = f32_to_bf16_rne(w - bf16_to_f32(hi));
        wefrag[(((0 * 4 + kb) * 4 + nt) * 64 + l) * 8 + j] = hi;
        wefrag[(((1 * 4 + kb) * 4 + nt) * 64 + l) * 8 + j] = lo;
    } else {
        int u = t - 8192;
        if (u >= 2 * 3 * 2 * 4 * 64 * 8) return;
        int j    = u & 7;
        int l    = (u >> 3) & 63;
        int nt   = (u >> 9) & 3;
        int kb   = (u >> 11) & 1;
        int mat  = (u >> 12) % 3;
        int layer = u / 12288;
        int kp = kb * 32 + 8 * (l >> 4) + j;       // position in A fragment
        int k  = (kp & 3) * 16 + (kp >> 2);        // sigma: original col there
        int n = nt * 16 + (l & 15);
        const float* Wm = (mat == 0) ? W1 : (mat == 1) ? W2 : W3;
        float w = Wm[(size_t)layer * HDIM * HDIM + k * HDIM + n];
        ushort_t hi = f32_to_bf16_rne(w);
        ushort_t lo = f32_to_bf16_rne(w - bf16_to_f32(hi));
        size_t base = (size_t)layer * 24576;
        wfrag[base + ((((size_t)(mat * 2 + 0) * 2 + kb) * 4 + nt) * 64 + l) * 8 + j] = hi;
        wfrag[base + ((((size_t)(mat * 2 + 1) * 2 + kb) * 4 + nt) * 64 + l) * 8 + j] = lo;
    }
}

// ---------------------------------------------------------------------------
// fused: emb via MFMA (blocks < EMB_BLOCKS) + p1 tile histogram (rest)
// ---------------------------------------------------------------------------
__global__ __launch_bounds__(256) void emb_p1(
    const float* __restrict__ x, const ushort_t* __restrict__ wefrag,
    const float* __restrict__ bemb, ushort_t* __restrict__ hbf,
    uchar_t* __restrict__ hq8,
    const int* __restrict__ dst, int* __restrict__ tileOff)
{
    __shared__ int hist[NBUCK];
    if (blockIdx.x < EMB_BLOCKS) {
        const int wid = blockIdx.x * 4 + (threadIdx.x >> 6);
        if (wid >= NNODES / 16) return;
        const int lane = threadIdx.x & 63;
        const int lrow = lane & 15;
        const int lgrp = lane >> 4;
        const int r0 = wid * 16;

        f32x4 acc[4];
#pragma unroll
        for (int nt = 0; nt < 4; ++nt) acc[nt] = (f32x4){0.f, 0.f, 0.f, 0.f};

#pragma unroll
        for (int kb = 0; kb < 4; ++kb) {
            const float* xp = x + (size_t)(r0 + lrow) * DINP + kb * 32 + lgrp * 8;
            float4 xa = *(const float4*)xp;
            float4 xb = *(const float4*)(xp + 4);
            bf16x8 xhi;
            xhi[0] = (short)f32_to_bf16_rne(xa.x);
            xhi[1] = (short)f32_to_bf16_rne(xa.y);
            xhi[2] = (short)f32_to_bf16_rne(xa.z);
            xhi[3] = (short)f32_to_bf16_rne(xa.w);
            xhi[4] = (short)f32_to_bf16_rne(xb.x);
            xhi[5] = (short)f32_to_bf16_rne(xb.y);
            xhi[6] = (short)f32_to_bf16_rne(xb.z);
            xhi[7] = (short)f32_to_bf16_rne(xb.w);
#pragma unroll
            for (int nt = 0; nt < 4; ++nt) {
                bf16x8 bhi = *(const bf16x8*)(wefrag + (((0 * 4 + kb) * 4 + nt) * 64 + lane) * 8);
                bf16x8 blo = *(const bf16x8*)(wefrag + (((1 * 4 + kb) * 4 + nt) * 64 + lane) * 8);
                acc[nt] = __builtin_amdgcn_mfma_f32_16x16x32_bf16(xhi, bhi, acc[nt], 0, 0, 0);
                acc[nt] = __builtin_amdgcn_mfma_f32_16x16x32_bf16(xhi, blo, acc[nt], 0, 0, 0);
            }
        }

        float bv[4];
#pragma unroll
        for (int nt = 0; nt < 4; ++nt) bv[nt] = bemb[nt * 16 + lrow];

#pragma unroll
        for (int r = 0; r < 4; ++r) {
            int row = r0 + lgrp * 4 + r;
            float o[4];
#pragma unroll
            for (int nt = 0; nt < 4; ++nt) o[nt] = acc[nt][r] + bv[nt];
            uint2 hb;
            hb.x = pack_bf16(o[0], o[1]);
            hb.y = pack_bf16(o[2], o[3]);
            *(uint2*)(hbf + ((size_t)row << 6) + (lrow << 2)) = hb;
            int q = __builtin_amdgcn_cvt_pk_fp8_f32(o[0], o[1], 0, false);
            q = __builtin_amdgcn_cvt_pk_fp8_f32(o[2], o[3], q, true);
            *(int*)(hq8 + ((size_t)row << 6) + (lrow << 2)) = q;
        }
    } else {
        const int tl = blockIdx.x - EMB_BLOCKS, t = threadIdx.x;
        hist[t] = 0;
        __syncthreads();
        const int base = tl * TILE;
#pragma unroll
        for (int i = 0; i < TILE / 256; ++i) {
            int e = base + i * 256 + t;
            if (e < NEDGES) atomicAdd(&hist[dst[e] / BDIV], 1);
        }
        __syncthreads();
        tileOff[t * NT + tl] = hist[t];
    }
}

// ---------------------------------------------------------------------------
// CSR build: p2 scan -> p3 bin (LDS cursors, 1024 thr) -> p4 sort
// ---------------------------------------------------------------------------
__global__ __launch_bounds__(1024) void p2_scan(int* __restrict__ tileOff)
{
    __shared__ int sd[1024];
    const int t = threadIdx.x;
    const int lo = t * SEG;
    int s = 0;
    for (int i = 0; i < SEG; ++i) s += tileOff[lo + i];
    sd[t] = s;
    __syncthreads();
    for (int off = 1; off < 1024; off <<= 1) {
        int v = (t >= off) ? sd[t - off] : 0;
        __syncthreads();
        sd[t] += v;
        __syncthreads();
    }
    int run = sd[t] - s;
    for (int i = 0; i < SEG; ++i) {
        int c = tileOff[lo + i];
        tileOff[lo + i] = run;
        run += c;
    }
}

// p3: bin edges into tmp; per-tile LDS cursors (write locality stays CU-local),
// 1024 threads/block to hide the LDS-atomic -> dependent-write chain
__global__ __launch_bounds__(1024) void p3_bin(
    const int* __restrict__ src, const int* __restrict__ dst,
    const float* __restrict__ attr, const int* __restrict__ tileOff,
    int2* __restrict__ tmp)
{
    __shared__ int cur[NBUCK];
    const int tl = blockIdx.x, t = threadIdx.x;
    if (t < NBUCK) cur[t] = tileOff[t * NT + tl];
    __syncthreads();
#pragma unroll
    for (int i = 0; i < TILE / 1024; ++i) {
        int e = tl * TILE + i * 1024 + t;
        if (e < NEDGES) {
            int d  = dst[e];
            int bk = d / BDIV;
            int ld = d - bk * BDIV;
            int pos = atomicAdd(&cur[bk], 1);
            int2 p;
            p.x = (ld << 17) | src[e];
            p.y = __float_as_int(attr[e]);
            tmp[pos] = p;
        }
    }
}

// per-bucket: hist+scan -> rowptr; scatter (src pre-scaled <<6); degw in LDS
__global__ __launch_bounds__(256) void p4_sort(
    const int2* __restrict__ tmp, const int* __restrict__ tileOff,
    int2* __restrict__ edgeS, int* __restrict__ rowptr,
    float* __restrict__ degw)
{
    __shared__ int sdh[512];
    __shared__ int cur[BDIV + 1];
    __shared__ float sdw[BDIV];
    const int b = blockIdx.x, t = threadIdx.x;
    const int n0 = b * BDIV;
    const int nn = (NNODES - n0 < BDIV) ? (NNODES - n0) : BDIV;
    const int ebeg = tileOff[b * NT];
    const int eend = (b + 1 < NBUCK) ? tileOff[(b + 1) * NT] : NEDGES;

    sdh[t] = 0; sdh[t + 256] = 0;
    for (int i = t; i < BDIV; i += 256) sdw[i] = 0.f;
    __syncthreads();
    for (int e = ebeg + t; e < eend; e += 256)
        atomicAdd(&sdh[tmp[e].x >> 17], 1);
    __syncthreads();
    for (int off = 1; off < 512; off <<= 1) {
        int i0 = t, i1 = t + 256;
        int v0 = (i0 >= off) ? sdh[i0 - off] : 0;
        int v1 = (i1 >= off) ? sdh[i1 - off] : 0;
        __syncthreads();
        sdh[i0] += v0; sdh[i1] += v1;
        __syncthreads();
    }
    for (int i = t; i < nn; i += 256) {
        int c = ebeg + (i ? sdh[i - 1] : 0);
        cur[i] = c;
        rowptr[n0 + i] = c;
    }
    if (b == NBUCK - 1 && t == 0) rowptr[NNODES] = NEDGES;
    __syncthreads();
    for (int e = ebeg + t; e < eend; e += 256) {
        int2 w = tmp[e];
        int ld = w.x >> 17;
        int pos = atomicAdd(&cur[ld], 1);
        atomicAdd(&sdw[ld], __int_as_float(w.y));
        int2 p;
        p.x = (w.x & 0x1FFFF) << 6;     // pre-scaled byte offset of src row
        p.y = w.y;
        edgeS[pos] = p;
    }
    __syncthreads();
    for (int i = t; i < nn; i += 256) degw[n0 + i] = sdw[i];
}

// ---------------------------------------------------------------------------
// gather: aggbf[v] = bf16( sum w_e * hq8[src_e] )
// FOUR nodes per wave (16 lanes each) -> 4 independent miss chains per wave.
// Within a 16-lane group: oct = edge slot (2/iter), ol = byte octet (8 fp8
// cols). Reduce = 1 shfl round (bit 3).
// ---------------------------------------------------------------------------
__global__ __launch_bounds__(256) void gather_kernel(
    const int* __restrict__ rowptr, const int2* __restrict__ edgeS,
    const uchar_t* __restrict__ hq8, ushort_t* __restrict__ aggbf)
{
    const int v   = blockIdx.x * 16 + (threadIdx.x >> 4);  // node per 16 lanes
    const int t4  = threadIdx.x & 15;
    const int oct = t4 >> 3;            // edge slot 0..1
    const int ol  = t4 & 7;             // cols 8*ol .. 8*ol+7 (perm positions)
    const int beg = rowptr[v], end = rowptr[v + 1];
    const int cnt = end - beg;
    const uchar_t* __restrict__ hq8o = hq8 + (ol << 3);
    const int2* __restrict__ ep = edgeS + beg + oct;

    float a0 = 0.f, a1 = 0.f, a2 = 0.f, a3 = 0.f;
    float a4 = 0.f, a5 = 0.f, a6 = 0.f, a7 = 0.f;
    const int nfull = cnt >> 1;
#pragma unroll 2
    for (int k = 0; k < nfull; ++k) {
        int2 ev = ep[(size_t)k * 2];
        float wv = __int_as_float(ev.y);
        uint2 u = *(const uint2*)(hq8o + ev.x);
        f32x2 f01 = __builtin_amdgcn_cvt_pk_f32_fp8((int)u.x, false);
        f32x2 f23 = __builtin_amdgcn_cvt_pk_f32_fp8((int)u.x, true);
        f32x2 f45 = __builtin_amdgcn_cvt_pk_f32_fp8((int)u.y, false);
        f32x2 f67 = __builtin_amdgcn_cvt_pk_f32_fp8((int)u.y, true);
        a0 += wv * f01[0];  a1 += wv * f01[1];
        a2 += wv * f23[0];  a3 += wv * f23[1];
        a4 += wv * f45[0];  a5 += wv * f45[1];
        a6 += wv * f67[0];  a7 += wv * f67[1];
    }
    if (cnt & 1) {
        int idx = beg + (nfull << 1) + oct;
        bool ok = idx < end;
        int2 ev = edgeS[ok ? idx : beg];
        float wv = ok ? __int_as_float(ev.y) : 0.f;
        uint2 u = *(const uint2*)(hq8o + ev.x);
        f32x2 f01 = __builtin_amdgcn_cvt_pk_f32_fp8((int)u.x, false);
        f32x2 f23 = __builtin_amdgcn_cvt_pk_f32_fp8((int)u.x, true);
        f32x2 f45 = __builtin_amdgcn_cvt_pk_f32_fp8((int)u.y, false);
        f32x2 f67 = __builtin_amdgcn_cvt_pk_f32_fp8((int)u.y, true);
        a0 += wv * f01[0];  a1 += wv * f01[1];
        a2 += wv * f23[0];  a3 += wv * f23[1];
        a4 += wv * f45[0];  a5 += wv * f45[1];
        a6 += wv * f67[0];  a7 += wv * f67[1];
    }

    // reduce across the 2 edge slots (lane bit 3) — stays within 16-lane group
    a0 += __shfl_xor(a0, 8);
    a1 += __shfl_xor(a1, 8);
    a2 += __shfl_xor(a2, 8);
    a3 += __shfl_xor(a3, 8);
    a4 += __shfl_xor(a4, 8);
    a5 += __shfl_xor(a5, 8);
    a6 += __shfl_xor(a6, 8);
    a7 += __shfl_xor(a7, 8);

    if (oct == 0) {
        uint4 o;
        o.x = pack_bf16(a0, a1);
        o.y = pack_bf16(a2, a3);
        o.z = pack_bf16(a4, a5);
        o.w = pack_bf16(a6, a7);
        *(uint4*)(aggbf + ((size_t)v << 6) + (ol << 3)) = o;
    }
}

// ---------------------------------------------------------------------------
// dense via MFMA (A operands permuted, wfrag sigma-compensated)
// ---------------------------------------------------------------------------
template<int WRITE_BF>
__global__ __launch_bounds__(256) void dense_mfma(
    const ushort_t* __restrict__ hbf, const ushort_t* __restrict__ aggbf,
    const float* __restrict__ degw, const ushort_t* __restrict__ wfrag,
    const float* __restrict__ b1, const float* __restrict__ b3,
    float* __restrict__ hout, ushort_t* __restrict__ hbf_out,
    uchar_t* __restrict__ hq8_out)
{
    const int wid = blockIdx.x * 4 + (threadIdx.x >> 6);
    if (wid >= NNODES / 16) return;
    const int lane = threadIdx.x & 63;
    const int lrow = lane & 15;
    const int lgrp = lane >> 4;
    const int r0   = wid * 16;

    f32x4 acc[3][4];
#pragma unroll
    for (int m = 0; m < 3; ++m)
#pragma unroll
        for (int nt = 0; nt < 4; ++nt)
            acc[m][nt] = (f32x4){0.f, 0.f, 0.f, 0.f};

#pragma unroll
    for (int kb = 0; kb < 2; ++kb) {
        const size_t aoff = ((size_t)(r0 + lrow) << 6) + kb * 32 + lgrp * 8;
        bf16x8 a_agg = *(const bf16x8*)(aggbf + aoff);
        bf16x8 a_h   = *(const bf16x8*)(hbf + aoff);
#pragma unroll
        for (int mv = 0; mv < 6; ++mv) {
            const int mat = mv >> 1;
            bf16x8 a = (mat == 0) ? a_agg : a_h;
            const ushort_t* wb = wfrag + (((size_t)mv * 2 + kb) * 4) * 512 + lane * 8;
#pragma unroll
            for (int nt = 0; nt < 4; ++nt) {
                bf16x8 b = *(const bf16x8*)(wb + nt * 512);
                acc[mat][nt] = __builtin_amdgcn_mfma_f32_16x16x32_bf16(
                    a, b, acc[mat][nt], 0, 0, 0);
            }
        }
    }

    float dreg[4];
#pragma unroll
    for (int r = 0; r < 4; ++r) dreg[r] = degw[r0 + lgrp * 4 + r];

    float b1v[4], b3v[4];
#pragma unroll
    for (int nt = 0; nt < 4; ++nt) {
        b1v[nt] = b1[nt * 16 + lrow];
        b3v[nt] = b3[nt * 16 + lrow];
    }

#pragma unroll
    for (int r = 0; r < 4; ++r) {
        int row = r0 + lgrp * 4 + r;
        float o[4];
#pragma unroll
        for (int nt = 0; nt < 4; ++nt) {
            float t = acc[0][nt][r] + acc[2][nt][r] - dreg[r] * acc[1][nt][r]
                    + dreg[r] * b1v[nt] + b3v[nt];
            o[nt] = fmaxf(t, 0.f);
        }
        if (WRITE_BF) {
            uint2 hb;
            hb.x = pack_bf16(o[0], o[1]);
            hb.y = pack_bf16(o[2], o[3]);
            *(uint2*)(hbf_out + ((size_t)row << 6) + (lrow << 2)) = hb;
            int q = __builtin_amdgcn_cvt_pk_fp8_f32(o[0], o[1], 0, false);
            q = __builtin_amdgcn_cvt_pk_fp8_f32(o[2], o[3], q, true);
            *(int*)(hq8_out + ((size_t)row << 6) + (lrow << 2)) = q;
        } else {
#pragma unroll
            for (int nt = 0; nt < 4; ++nt)
                hout[((size_t)row << 6) + nt * 16 + lrow] = o[nt];
        }
    }
}

// ---------------------------------------------------------------------------
extern "C" void kernel_launch(void* const* d_in, const int* in_sizes, int n_in,
                              void* d_out, int out_size, void* d_ws, size_t ws_size,
                              hipStream_t stream)
{
    const float* x    = (const float*)d_in[0];
    const int*   eidx = (const int*)  d_in[1];
    const float* attr = (const float*)d_in[2];
    const float* Wemb = (const float*)d_in[4];
    const float* bemb = (const float*)d_in[5];
    const float* W1   = (const float*)d_in[6];
    const float* b1   = (const float*)d_in[7];
    const float* W2   = (const float*)d_in[8];
    const float* W3   = (const float*)d_in[9];
    const float* b3   = (const float*)d_in[10];

    float* hout = (float*)d_out;

    // workspace layout (4B units)
    float*    degw    = (float*)d_ws;                            // N
    int*      rowptr  = (int*)d_ws + 100000;                     // N+1
    int*      tileOff = (int*)d_ws + 200016;                     // NTOT
    int2*     edgeS   = (int2*)((int*)d_ws + 250192);            // E int2
    ushort_t* hbf     = (ushort_t*)((int*)d_ws + 3450192);       // N*64 bf16 (permuted)
    ushort_t* aggbf   = (ushort_t*)((int*)d_ws + 6650192);       // N*64 bf16 (permuted)
    int2*     tmp     = (int2*)aggbf;                            // alias (CSR build)
    ushort_t* wfrag   = (ushort_t*)((int*)d_ws + 9850192);       // 49152 ushorts
    ushort_t* wefrag  = (ushort_t*)((int*)d_ws + 9874768);       // 16384 ushorts
    uchar_t*  hq8     = (uchar_t*)((int*)d_ws + 9882960);        // N*64 fp8 (permuted)

    const int* srcI = eidx;
    const int* dstI = eidx + NEDGES;

    wprep_all<<<128, 256, 0, stream>>>(Wemb, W1, W2, W3, wefrag, wfrag);

    emb_p1<<<EMB_BLOCKS + NT, 256, 0, stream>>>(
        x, wefrag, bemb, hbf, hq8, dstI, tileOff);

    p2_scan<<<1, 1024, 0, stream>>>(tileOff);
    p3_bin <<<NT, 1024, 0, stream>>>(srcI, dstI, attr, tileOff, tmp);
    p4_sort<<<NBUCK, 256, 0, stream>>>(tmp, tileOff, edgeS, rowptr, degw);

    const int mfmaGrid = (NNODES / 16 + 3) / 4;   // 1563
    const int gatherGrid = NNODES / 16;           // 4 nodes/wave, 4 waves/block
    // layer 0: writes hbf + hq8
    gather_kernel<<<gatherGrid, 256, 0, stream>>>(rowptr, edgeS, hq8, aggbf);
    dense_mfma<1><<<mfmaGrid, 256, 0, stream>>>(
        hbf, aggbf, degw, wfrag, b1, b3, hout, hbf, hq8);
    // layer 1: writes fp32 output
    gather_kernel<<<gatherGrid, 256, 0, stream>>>(rowptr, edgeS, hq8, aggbf);
    dense_mfma<0><<<mfmaGrid, 256, 0, stream>>>(
        hbf, aggbf, degw, wfrag + 24576, b1 + HDIM, b3 + HDIM, hout, hbf, hq8);
}

// Round 18
// 178.901 us; speedup vs baseline: 1.6951x; 1.0236x over previous
//
#include <hip/hip_runtime.h>

#define NNODES 100000
#define NEDGES 1600000
#define DINP   128
#define HDIM   64
#define NLAYERS 2

#define NBUCK 256
#define BDIV  391
#define TILE  8192
#define NT    ((NEDGES + TILE - 1) / TILE)     // 196
#define NTOT  (NBUCK * NT)                     // 50176
#define SEG   (NTOT / 1024)                    // 49
#define EMB_BLOCKS 1563                        // ceil(6250 waves / 4)

typedef unsigned short ushort_t;
typedef unsigned int   uint_t;
typedef unsigned char  uchar_t;
typedef __attribute__((ext_vector_type(8))) short bf16x8;
typedef __attribute__((ext_vector_type(4))) float f32x4;
typedef __attribute__((ext_vector_type(2))) float f32x2;

__device__ __forceinline__ ushort_t f32_to_bf16_rne(float x) {
    uint_t u = __float_as_uint(x);
    u = (u + 0x7FFFu + ((u >> 16) & 1u)) >> 16;
    return (ushort_t)u;
}
__device__ __forceinline__ float bf16_to_f32(ushort_t v) {
    return __uint_as_float(((uint_t)v) << 16);
}
__device__ __forceinline__ uint_t pack_bf16(float lo, float hi) {
    return (uint_t)f32_to_bf16_rne(lo) | ((uint_t)f32_to_bf16_rne(hi) << 16);
}

// sigma-permuted column layout: original col c stored at pos 4*(c&15)+(c>>4);
// pos p holds col (p&3)*16 + (p>>2). Applied to hbf/hq8/aggbf; compensated in
// wprep by permuting k. dense<0> fp32 output remains standard.

// ---------------------------------------------------------------------------
// fused wprep: emb B-fragments (t<8192) + W1/W2/W3 B-fragments (t>=8192)
// ---------------------------------------------------------------------------
__global__ __launch_bounds__(256) void wprep_all(
    const float* __restrict__ Wemb, const float* __restrict__ W1,
    const float* __restrict__ W2, const float* __restrict__ W3,
    ushort_t* __restrict__ wefrag, ushort_t* __restrict__ wfrag)
{
    int t = blockIdx.x * 256 + threadIdx.x;
    if (t < 8192) {
        int j  = t & 7;
        int l  = (t >> 3) & 63;
        int nt = (t >> 9) & 3;
        int kb = (t >> 11) & 3;
        int k = kb * 32 + 8 * (l >> 4) + j;
        int n = nt * 16 + (l & 15);
        float w = Wemb[k * HDIM + n];
        ushort_t hi = f32_to_bf16_rne(w);
        ushort_t lo = f32_to_bf16_rne(w - bf16_to_f32(hi));
        wefrag[(((0 * 4 + kb) * 4 + nt) * 64 + l) * 8 + j] = hi;
        wefrag[(((1 * 4 + kb) * 4 + nt) * 64 + l) * 8 + j] = lo;
    } else {
        int u = t - 8192;
        if (u >= 2 * 3 * 2 * 4 * 64 * 8) return;
        int j    = u & 7;
        int l    = (u >> 3) & 63;
        int nt   = (u >> 9) & 3;
        int kb   = (u >> 11) & 1;
        int mat  = (u >> 12) % 3;
        int layer = u / 12288;
        int kp = kb * 32 + 8 * (l >> 4) + j;       // position in A fragment
        int k  = (kp & 3) * 16 + (kp >> 2);        // sigma: original col there
        int n = nt * 16 + (l & 15);
        const float* Wm = (mat == 0) ? W1 : (mat == 1) ? W2 : W3;
        float w = Wm[(size_t)layer * HDIM * HDIM + k * HDIM + n];
        ushort_t hi = f32_to_bf16_rne(w);
        ushort_t lo = f32_to_bf16_rne(w - bf16_to_f32(hi));
        size_t base = (size_t)layer * 24576;
        wfrag[base + ((((size_t)(mat * 2 + 0) * 2 + kb) * 4 + nt) * 64 + l) * 8 + j] = hi;
        wfrag[base + ((((size_t)(mat * 2 + 1) * 2 + kb) * 4 + nt) * 64 + l) * 8 + j] = lo;
    }
}

// ---------------------------------------------------------------------------
// fused: emb via MFMA (blocks < EMB_BLOCKS) + p1 tile histogram (rest)
// ---------------------------------------------------------------------------
__global__ __launch_bounds__(256) void emb_p1(
    const float* __restrict__ x, const ushort_t* __restrict__ wefrag,
    const float* __restrict__ bemb, ushort_t* __restrict__ hbf,
    uchar_t* __restrict__ hq8,
    const int* __restrict__ dst, int* __restrict__ tileOff)
{
    __shared__ int hist[NBUCK];
    if (blockIdx.x < EMB_BLOCKS) {
        const int wid = blockIdx.x * 4 + (threadIdx.x >> 6);
        if (wid >= NNODES / 16) return;
        const int lane = threadIdx.x & 63;
        const int lrow = lane & 15;
        const int lgrp = lane >> 4;
        const int r0 = wid * 16;

        f32x4 acc[4];
#pragma unroll
        for (int nt = 0; nt < 4; ++nt) acc[nt] = (f32x4){0.f, 0.f, 0.f, 0.f};

#pragma unroll
        for (int kb = 0; kb < 4; ++kb) {
            const float* xp = x + (size_t)(r0 + lrow) * DINP + kb * 32 + lgrp * 8;
            float4 xa = *(const float4*)xp;
            float4 xb = *(const float4*)(xp + 4);
            bf16x8 xhi;
            xhi[0] = (short)f32_to_bf16_rne(xa.x);
            xhi[1] = (short)f32_to_bf16_rne(xa.y);
            xhi[2] = (short)f32_to_bf16_rne(xa.z);
            xhi[3] = (short)f32_to_bf16_rne(xa.w);
            xhi[4] = (short)f32_to_bf16_rne(xb.x);
            xhi[5] = (short)f32_to_bf16_rne(xb.y);
            xhi[6] = (short)f32_to_bf16_rne(xb.z);
            xhi[7] = (short)f32_to_bf16_rne(xb.w);
#pragma unroll
            for (int nt = 0; nt < 4; ++nt) {
                bf16x8 bhi = *(const bf16x8*)(wefrag + (((0 * 4 + kb) * 4 + nt) * 64 + lane) * 8);
                bf16x8 blo = *(const bf16x8*)(wefrag + (((1 * 4 + kb) * 4 + nt) * 64 + lane) * 8);
                acc[nt] = __builtin_amdgcn_mfma_f32_16x16x32_bf16(xhi, bhi, acc[nt], 0, 0, 0);
                acc[nt] = __builtin_amdgcn_mfma_f32_16x16x32_bf16(xhi, blo, acc[nt], 0, 0, 0);
            }
        }

        float bv[4];
#pragma unroll
        for (int nt = 0; nt < 4; ++nt) bv[nt] = bemb[nt * 16 + lrow];

#pragma unroll
        for (int r = 0; r < 4; ++r) {
            int row = r0 + lgrp * 4 + r;
            float o[4];
#pragma unroll
            for (int nt = 0; nt < 4; ++nt) o[nt] = acc[nt][r] + bv[nt];
            uint2 hb;
            hb.x = pack_bf16(o[0], o[1]);
            hb.y = pack_bf16(o[2], o[3]);
            *(uint2*)(hbf + ((size_t)row << 6) + (lrow << 2)) = hb;
            int q = __builtin_amdgcn_cvt_pk_fp8_f32(o[0], o[1], 0, false);
            q = __builtin_amdgcn_cvt_pk_fp8_f32(o[2], o[3], q, true);
            *(int*)(hq8 + ((size_t)row << 6) + (lrow << 2)) = q;
        }
    } else {
        const int tl = blockIdx.x - EMB_BLOCKS, t = threadIdx.x;
        hist[t] = 0;
        __syncthreads();
        const int base = tl * TILE;
#pragma unroll
        for (int i = 0; i < TILE / 256; ++i) {
            int e = base + i * 256 + t;
            if (e < NEDGES) atomicAdd(&hist[dst[e] / BDIV], 1);
        }
        __syncthreads();
        tileOff[t * NT + tl] = hist[t];
    }
}

// ---------------------------------------------------------------------------
// CSR build: p2 scan -> p3 bin (LDS cursors, 1024 thr) -> p4 sort (1024 thr)
// ---------------------------------------------------------------------------
__global__ __launch_bounds__(1024) void p2_scan(int* __restrict__ tileOff)
{
    __shared__ int sd[1024];
    const int t = threadIdx.x;
    const int lo = t * SEG;
    int s = 0;
    for (int i = 0; i < SEG; ++i) s += tileOff[lo + i];
    sd[t] = s;
    __syncthreads();
    for (int off = 1; off < 1024; off <<= 1) {
        int v = (t >= off) ? sd[t - off] : 0;
        __syncthreads();
        sd[t] += v;
        __syncthreads();
    }
    int run = sd[t] - s;
    for (int i = 0; i < SEG; ++i) {
        int c = tileOff[lo + i];
        tileOff[lo + i] = run;
        run += c;
    }
}

// p3: bin edges into tmp; per-tile LDS cursors (write locality stays CU-local)
__global__ __launch_bounds__(1024) void p3_bin(
    const int* __restrict__ src, const int* __restrict__ dst,
    const float* __restrict__ attr, const int* __restrict__ tileOff,
    int2* __restrict__ tmp)
{
    __shared__ int cur[NBUCK];
    const int tl = blockIdx.x, t = threadIdx.x;
    if (t < NBUCK) cur[t] = tileOff[t * NT + tl];
    __syncthreads();
#pragma unroll
    for (int i = 0; i < TILE / 1024; ++i) {
        int e = tl * TILE + i * 1024 + t;
        if (e < NEDGES) {
            int d  = dst[e];
            int bk = d / BDIV;
            int ld = d - bk * BDIV;
            int pos = atomicAdd(&cur[bk], 1);
            int2 p;
            p.x = (ld << 17) | src[e];
            p.y = __float_as_int(attr[e]);
            tmp[pos] = p;
        }
    }
}

// per-bucket: hist+scan -> rowptr; scatter (src pre-scaled <<6); degw in LDS
// 1024 threads: ~6 edges/thread, deep latency hiding
__global__ __launch_bounds__(1024) void p4_sort(
    const int2* __restrict__ tmp, const int* __restrict__ tileOff,
    int2* __restrict__ edgeS, int* __restrict__ rowptr,
    float* __restrict__ degw)
{
    __shared__ int sdh[512];
    __shared__ int cur[BDIV + 1];
    __shared__ float sdw[BDIV];
    const int b = blockIdx.x, t = threadIdx.x;
    const int n0 = b * BDIV;
    const int nn = (NNODES - n0 < BDIV) ? (NNODES - n0) : BDIV;
    const int ebeg = tileOff[b * NT];
    const int eend = (b + 1 < NBUCK) ? tileOff[(b + 1) * NT] : NEDGES;

    if (t < 512) sdh[t] = 0;
    for (int i = t; i < BDIV; i += 1024) sdw[i] = 0.f;
    __syncthreads();
    for (int e = ebeg + t; e < eend; e += 1024)
        atomicAdd(&sdh[tmp[e].x >> 17], 1);
    __syncthreads();
    // inclusive Hillis-Steele over 512 entries (threads 0-511 active)
    for (int off = 1; off < 512; off <<= 1) {
        int v = (t >= off && t < 512) ? sdh[t - off] : 0;
        __syncthreads();
        if (t < 512) sdh[t] += v;
        __syncthreads();
    }
    for (int i = t; i < nn; i += 1024) {
        int c = ebeg + (i ? sdh[i - 1] : 0);
        cur[i] = c;
        rowptr[n0 + i] = c;
    }
    if (b == NBUCK - 1 && t == 0) rowptr[NNODES] = NEDGES;
    __syncthreads();
    for (int e = ebeg + t; e < eend; e += 1024) {
        int2 w = tmp[e];
        int ld = w.x >> 17;
        int pos = atomicAdd(&cur[ld], 1);
        atomicAdd(&sdw[ld], __int_as_float(w.y));
        int2 p;
        p.x = (w.x & 0x1FFFF) << 6;     // pre-scaled byte offset of src row
        p.y = w.y;
        edgeS[pos] = p;
    }
    __syncthreads();
    for (int i = t; i < nn; i += 1024) degw[n0 + i] = sdw[i];
}

// ---------------------------------------------------------------------------
// gather: aggbf[v] = bf16( sum w_e * hq8[src_e] )
// EIGHT nodes per wave (8 lanes/node), one edge per group-iteration:
// group broadcast-loads the 8 B edge (1 VMEM/wave) + contiguous 64 B row
// (8 x 8 B, 1 VMEM/wave). 8 independent miss chains/wave; ZERO shuffles;
// each lane stores its own 16 B of aggbf.
// ---------------------------------------------------------------------------
__global__ __launch_bounds__(256) void gather_kernel(
    const int* __restrict__ rowptr, const int2* __restrict__ edgeS,
    const uchar_t* __restrict__ hq8, ushort_t* __restrict__ aggbf)
{
    const int v  = blockIdx.x * 32 + (threadIdx.x >> 3);   // node per 8 lanes
    const int ol = threadIdx.x & 7;     // byte octet: perm cols 8*ol..8*ol+7
    const int beg = rowptr[v], end = rowptr[v + 1];
    const uchar_t* __restrict__ hq8o = hq8 + (ol << 3);
    const int2* __restrict__ ep = edgeS + beg;
    const int cnt = end - beg;

    float a0 = 0.f, a1 = 0.f, a2 = 0.f, a3 = 0.f;
    float a4 = 0.f, a5 = 0.f, a6 = 0.f, a7 = 0.f;
#pragma unroll 2
    for (int k = 0; k < cnt; ++k) {
        int2 ev = ep[k];                 // 8 lanes broadcast-load 8 B
        float wv = __int_as_float(ev.y);
        uint2 u = *(const uint2*)(hq8o + ev.x);
        f32x2 f01 = __builtin_amdgcn_cvt_pk_f32_fp8((int)u.x, false);
        f32x2 f23 = __builtin_amdgcn_cvt_pk_f32_fp8((int)u.x, true);
        f32x2 f45 = __builtin_amdgcn_cvt_pk_f32_fp8((int)u.y, false);
        f32x2 f67 = __builtin_amdgcn_cvt_pk_f32_fp8((int)u.y, true);
        a0 += wv * f01[0];  a1 += wv * f01[1];
        a2 += wv * f23[0];  a3 += wv * f23[1];
        a4 += wv * f45[0];  a5 += wv * f45[1];
        a6 += wv * f67[0];  a7 += wv * f67[1];
    }

    uint4 o;
    o.x = pack_bf16(a0, a1);
    o.y = pack_bf16(a2, a3);
    o.z = pack_bf16(a4, a5);
    o.w = pack_bf16(a6, a7);
    *(uint4*)(aggbf + ((size_t)v << 6) + (ol << 3)) = o;
}

// ---------------------------------------------------------------------------
// dense via MFMA (A operands permuted, wfrag sigma-compensated)
// ---------------------------------------------------------------------------
template<int WRITE_BF>
__global__ __launch_bounds__(256) void dense_mfma(
    const ushort_t* __restrict__ hbf, const ushort_t* __restrict__ aggbf,
    const float* __restrict__ degw, const ushort_t* __restrict__ wfrag,
    const float* __restrict__ b1, const float* __restrict__ b3,
    float* __restrict__ hout, ushort_t* __restrict__ hbf_out,
    uchar_t* __restrict__ hq8_out)
{
    const int wid = blockIdx.x * 4 + (threadIdx.x >> 6);
    if (wid >= NNODES / 16) return;
    const int lane = threadIdx.x & 63;
    const int lrow = lane & 15;
    const int lgrp = lane >> 4;
    const int r0   = wid * 16;

    f32x4 acc[3][4];
#pragma unroll
    for (int m = 0; m < 3; ++m)
#pragma unroll
        for (int nt = 0; nt < 4; ++nt)
            acc[m][nt] = (f32x4){0.f, 0.f, 0.f, 0.f};

#pragma unroll
    for (int kb = 0; kb < 2; ++kb) {
        const size_t aoff = ((size_t)(r0 + lrow) << 6) + kb * 32 + lgrp * 8;
        bf16x8 a_agg = *(const bf16x8*)(aggbf + aoff);
        bf16x8 a_h   = *(const bf16x8*)(hbf + aoff);
#pragma unroll
        for (int mv = 0; mv < 6; ++mv) {
            const int mat = mv >> 1;
            bf16x8 a = (mat == 0) ? a_agg : a_h;
            const ushort_t* wb = wfrag + (((size_t)mv * 2 + kb) * 4) * 512 + lane * 8;
#pragma unroll
            for (int nt = 0; nt < 4; ++nt) {
                bf16x8 b = *(const bf16x8*)(wb + nt * 512);
                acc[mat][nt] = __builtin_amdgcn_mfma_f32_16x16x32_bf16(
                    a, b, acc[mat][nt], 0, 0, 0);
            }
        }
    }

    float dreg[4];
#pragma unroll
    for (int r = 0; r < 4; ++r) dreg[r] = degw[r0 + lgrp * 4 + r];

    float b1v[4], b3v[4];
#pragma unroll
    for (int nt = 0; nt < 4; ++nt) {
        b1v[nt] = b1[nt * 16 + lrow];
        b3v[nt] = b3[nt * 16 + lrow];
    }

#pragma unroll
    for (int r = 0; r < 4; ++r) {
        int row = r0 + lgrp * 4 + r;
        float o[4];
#pragma unroll
        for (int nt = 0; nt < 4; ++nt) {
            float t = acc[0][nt][r] + acc[2][nt][r] - dreg[r] * acc[1][nt][r]
                    + dreg[r] * b1v[nt] + b3v[nt];
            o[nt] = fmaxf(t, 0.f);
        }
        if (WRITE_BF) {
            uint2 hb;
            hb.x = pack_bf16(o[0], o[1]);
            hb.y = pack_bf16(o[2], o[3]);
            *(uint2*)(hbf_out + ((size_t)row << 6) + (lrow << 2)) = hb;
            int q = __builtin_amdgcn_cvt_pk_fp8_f32(o[0], o[1], 0, false);
            q = __builtin_amdgcn_cvt_pk_fp8_f32(o[2], o[3], q, true);
            *(int*)(hq8_out + ((size_t)row << 6) + (lrow << 2)) = q;
        } else {
#pragma unroll
            for (int nt = 0; nt < 4; ++nt)
                hout[((size_t)row << 6) + nt * 16 + lrow] = o[nt];
        }
    }
}

// ---------------------------------------------------------------------------
extern "C" void kernel_launch(void* const* d_in, const int* in_sizes, int n_in,
                              void* d_out, int out_size, void* d_ws, size_t ws_size,
                              hipStream_t stream)
{
    const float* x    = (const float*)d_in[0];
    const int*   eidx = (const int*)  d_in[1];
    const float* attr = (const float*)d_in[2];
    const float* Wemb = (const float*)d_in[4];
    const float* bemb = (const float*)d_in[5];
    const float* W1   = (const float*)d_in[6];
    const float* b1   = (const float*)d_in[7];
    const float* W2   = (const float*)d_in[8];
    const float* W3   = (const float*)d_in[9];
    const float* b3   = (const float*)d_in[10];

    float* hout = (float*)d_out;

    // workspace layout (4B units)
    float*    degw    = (float*)d_ws;                            // N
    int*      rowptr  = (int*)d_ws + 100000;                     // N+1
    int*      tileOff = (int*)d_ws + 200016;                     // NTOT
    int2*     edgeS   = (int2*)((int*)d_ws + 250192);            // E int2
    ushort_t* hbf     = (ushort_t*)((int*)d_ws + 3450192);       // N*64 bf16 (permuted)
    ushort_t* aggbf   = (ushort_t*)((int*)d_ws + 6650192);       // N*64 bf16 (permuted)
    int2*     tmp     = (int2*)aggbf;                            // alias (CSR build)
    ushort_t* wfrag   = (ushort_t*)((int*)d_ws + 9850192);       // 49152 ushorts
    ushort_t* wefrag  = (ushort_t*)((int*)d_ws + 9874768);       // 16384 ushorts
    uchar_t*  hq8     = (uchar_t*)((int*)d_ws + 9882960);        // N*64 fp8 (permuted)

    const int* srcI = eidx;
    const int* dstI = eidx + NEDGES;

    wprep_all<<<128, 256, 0, stream>>>(Wemb, W1, W2, W3, wefrag, wfrag);

    emb_p1<<<EMB_BLOCKS + NT, 256, 0, stream>>>(
        x, wefrag, bemb, hbf, hq8, dstI, tileOff);

    p2_scan<<<1, 1024, 0, stream>>>(tileOff);
    p3_bin <<<NT, 1024, 0, stream>>>(srcI, dstI, attr, tileOff, tmp);
    p4_sort<<<NBUCK, 1024, 0, stream>>>(tmp, tileOff, edgeS, rowptr, degw);

    const int mfmaGrid = (NNODES / 16 + 3) / 4;   // 1563
    const int gatherGrid = NNODES / 32;           // 8 nodes/wave, 4 waves/block
    // layer 0: writes hbf + hq8
    gather_kernel<<<gatherGrid, 256, 0, stream>>>(rowptr, edgeS, hq8, aggbf);
    dense_mfma<1><<<mfmaGrid, 256, 0, stream>>>(
        hbf, aggbf, degw, wfrag, b1, b3, hout, hbf, hq8);
    // layer 1: writes fp32 output
    gather_kernel<<<gatherGrid, 256, 0, stream>>>(rowptr, edgeS, hq8, aggbf);
    dense_mfma<0><<<mfmaGrid, 256, 0, stream>>>(
        hbf, aggbf, degw, wfrag + 24576, b1 + HDIM, b3 + HDIM, hout, hbf, hq8);
}